// Round 2
// baseline (890.347 us; speedup 1.0000x reference)
//
#include <hip/hip_runtime.h>

#define NN 50000
#define EE 800000
#define ET (EE + NN)
#define HID 256
#define NH 8
#define HC 32
#define OC 64

typedef unsigned int u32;
typedef __bf16 bf16;
typedef __attribute__((ext_vector_type(8))) __bf16 bf16x8;
typedef __attribute__((ext_vector_type(4))) float f32x4;

static __device__ __forceinline__ float geluf(float x){
  float t = tanhf(0.7978845608028654f*(x + 0.044715f*x*x*x));
  return 0.5f*x*(1.0f+t);
}
static __device__ __forceinline__ float leakyf(float x){
  return x > 0.0f ? x : 0.2f*x;
}

// ---------------- CSR build ----------------
__global__ void k_init(u32* cnt, u32* counter){
  int i = blockIdx.x*blockDim.x + threadIdx.x;
  if (i < NN) cnt[i] = 1u;            // self loop
  if (i == 0) counter[0] = 0u;
}
__global__ void k_count(const int* __restrict__ dst, u32* __restrict__ cnt){
  int e = blockIdx.x*blockDim.x + threadIdx.x;
  if (e < EE) atomicAdd(&cnt[dst[e]], 1u);
}
__global__ void k_alloc(const u32* __restrict__ cnt, u32* counter,
                        u32* __restrict__ start, u32* __restrict__ pos){
  int n = blockIdx.x*blockDim.x + threadIdx.x;
  if (n < NN){ u32 s = atomicAdd(counter, cnt[n]); start[n] = s; pos[n] = s; }
}
__global__ void k_fill(const int* __restrict__ src, const int* __restrict__ dst,
                       u32* __restrict__ pos, u32* __restrict__ col){
  int e = blockIdx.x*blockDim.x + threadIdx.x;
  if (e < ET){
    int s, d;
    if (e < EE){ s = src[e]; d = dst[e]; } else { s = d = e - EE; }
    u32 idx = atomicAdd(&pos[d], 1u);
    col[idx] = (u32)s;
  }
}
__global__ void k_dinv(const u32* __restrict__ cnt, float* __restrict__ dinv){
  int n = blockIdx.x*blockDim.x + threadIdx.x;
  if (n < NN) dinv[n] = rsqrtf((float)cnt[n]);
}

// ---------------- weight split: W[K=256][NCOLS] f32 -> Whi/Wlo[c][k] bf16 (col-major) ----------------
template<int NCOLS>
__global__ void k_wsplit(const float* __restrict__ W, bf16* __restrict__ Whi, bf16* __restrict__ Wlo){
  int e = blockIdx.x*blockDim.x + threadIdx.x;
  if (e >= NCOLS*HID) return;
  int c = e / HID, k = e % HID;
  float w = W[(size_t)k*NCOLS + c];
  bf16 hi = (bf16)w;
  bf16 lo = (bf16)(w - (float)hi);
  Whi[(size_t)c*HID + k] = hi;
  Wlo[(size_t)c*HID + k] = lo;
}

// ---------------- GCN aggregation: wave per node, 64 lanes x 4 f32 feats ----------------
__global__ __launch_bounds__(256) void k_agg(const float* __restrict__ feat,
    const u32* __restrict__ col, const u32* __restrict__ start, const u32* __restrict__ cnt,
    const float* __restrict__ dinv, float* __restrict__ out){
  const int n = (int)((blockIdx.x*blockDim.x + threadIdx.x) >> 6);
  if (n >= NN) return;
  const int lane = threadIdx.x & 63;
  const u32 b = start[n], e = b + cnt[n];
  const float dd = dinv[n];
  const int fo = lane*4;
  float a0=0.f,a1=0.f,a2=0.f,a3=0.f;
  for (u32 k=b; k<e; ++k){
    const u32 s = col[k];
    const float nrm = dd * dinv[s];
    const float4 v = *(const float4*)(feat + (size_t)s*HID + fo);
    a0 = fmaf(nrm, v.x, a0);
    a1 = fmaf(nrm, v.y, a1);
    a2 = fmaf(nrm, v.z, a2);
    a3 = fmaf(nrm, v.w, a3);
  }
  *(float4*)(out + (size_t)n*HID + fo) = make_float4(a0,a1,a2,a3);
}

// ---------------- split-bf16 MFMA GEMM: C[M,NCOLS] = act(A[M,256] @ W + bias) ----------------
// A f32; W pre-split col-major bf16 hi/lo; C f32. block=256thr(4 waves), 16 rows/block.
// 3-pass split: A*W ~= ahi*whi + ahi*wlo + alo*whi  (rel err ~2^-18)
template<int NCOLS, int NF, int ACT>
__global__ __launch_bounds__(256) void k_gemm(const float* __restrict__ A,
    const bf16* __restrict__ Whi, const bf16* __restrict__ Wlo,
    const float* __restrict__ bias, float* __restrict__ Cout){
  const int tid = threadIdx.x;
  const int w = tid >> 6, lane = tid & 63;
  const int r = lane & 15, g = lane >> 4;     // C/D: col=lane&15, row=(lane>>4)*4+reg
  const int bm = blockIdx.x;
  const int grow = bm*16 + r;
  const int wcol = w * (NF*16);
  f32x4 acc[NF];
  #pragma unroll
  for (int j=0;j<NF;++j){ f32x4 z = {0.f,0.f,0.f,0.f}; acc[j] = z; }
  #pragma unroll
  for (int kk=0; kk<8; ++kk){
    const int k0 = kk*32 + g*8;               // A: row=lane&15, k=(lane>>4)*8+i
    const float* ap = A + (size_t)grow*HID + k0;
    const float4 u0 = *(const float4*)ap;
    const float4 u1 = *(const float4*)(ap+4);
    float af[8] = {u0.x,u0.y,u0.z,u0.w,u1.x,u1.y,u1.z,u1.w};
    bf16x8 ahi, alo;
    #pragma unroll
    for (int i=0;i<8;++i){
      bf16 h = (bf16)af[i];
      ahi[i] = h;
      alo[i] = (bf16)(af[i] - (float)h);
    }
    #pragma unroll
    for (int j=0;j<NF;++j){
      const int c = wcol + j*16 + r;          // B: col=lane&15, k=(lane>>4)*8+i
      const size_t off = (size_t)c*HID + k0;
      const bf16x8 wh = *(const bf16x8*)(Whi + off);
      const bf16x8 wl = *(const bf16x8*)(Wlo + off);
      acc[j] = __builtin_amdgcn_mfma_f32_16x16x32_bf16(ahi, wh, acc[j], 0, 0, 0);
      acc[j] = __builtin_amdgcn_mfma_f32_16x16x32_bf16(ahi, wl, acc[j], 0, 0, 0);
      acc[j] = __builtin_amdgcn_mfma_f32_16x16x32_bf16(alo, wh, acc[j], 0, 0, 0);
    }
  }
  #pragma unroll
  for (int j=0;j<NF;++j){
    const int c = wcol + j*16 + r;
    const float bv = bias ? bias[c] : 0.f;
    #pragma unroll
    for (int q=0;q<4;++q){
      const int row = bm*16 + g*4 + q;
      float v = acc[j][q] + bv;
      if (ACT==1) v = geluf(v);
      Cout[(size_t)row*NCOLS + c] = v;
    }
  }
}

// ---------------- GAT: per-node attention coefficients ----------------
__global__ __launch_bounds__(256) void k_attcoef(const float* __restrict__ gfeat,
    const float* __restrict__ atts, const float* __restrict__ attd,
    float* __restrict__ a_src, float* __restrict__ a_dst){
  const int n = (int)((blockIdx.x*blockDim.x + threadIdx.x) >> 6);
  if (n >= NN) return;
  const int lane = threadIdx.x & 63;
  const int head = lane >> 3, sub = lane & 7;
  const int off = head*HC + sub*4;
  const float4 gv = *(const float4*)(gfeat + (size_t)n*HID + off);
  const float4 sv = *(const float4*)(atts + off);
  const float4 dv = *(const float4*)(attd + off);
  float ps = gv.x*sv.x + gv.y*sv.y + gv.z*sv.z + gv.w*sv.w;
  float pd = gv.x*dv.x + gv.y*dv.y + gv.z*dv.z + gv.w*dv.w;
  ps += __shfl_xor(ps,1); ps += __shfl_xor(ps,2); ps += __shfl_xor(ps,4);
  pd += __shfl_xor(pd,1); pd += __shfl_xor(pd,2); pd += __shfl_xor(pd,4);
  if (sub == 0){ a_src[n*NH+head] = ps; a_dst[n*NH+head] = pd; }
}

// ---------------- GAT: segment max + sum (wave per node, 8 edges x 8 heads) ----------------
__global__ __launch_bounds__(256) void k_gat_ms(const u32* __restrict__ col,
    const u32* __restrict__ start, const u32* __restrict__ cnt,
    const float* __restrict__ a_src, const float* __restrict__ a_dst,
    float* __restrict__ marr, float* __restrict__ sarr){
  const int n = (int)((blockIdx.x*blockDim.x + threadIdx.x) >> 6);
  if (n >= NN) return;
  const int lane = threadIdx.x & 63;
  const int h = lane & 7, e8 = lane >> 3;
  const u32 b = start[n], c = cnt[n];
  const float ad = a_dst[n*NH+h];
  float vmax = -1e30f;
  for (u32 k0=0; k0<c; k0+=8){
    const u32 ke = k0 + (u32)e8;
    float l = -1e30f;
    if (ke < c){
      const u32 s = col[b+ke];
      l = leakyf(a_src[s*NH+h] + ad);
    }
    l = fmaxf(l, __shfl_xor(l,8));
    l = fmaxf(l, __shfl_xor(l,16));
    l = fmaxf(l, __shfl_xor(l,32));
    vmax = fmaxf(vmax, l);
  }
  float ss = 0.f;
  for (u32 k0=0; k0<c; k0+=8){
    const u32 ke = k0 + (u32)e8;
    float p = 0.f;
    if (ke < c){
      const u32 s = col[b+ke];
      p = expf(leakyf(a_src[s*NH+h] + ad) - vmax);
    }
    p += __shfl_xor(p,8); p += __shfl_xor(p,16); p += __shfl_xor(p,32);
    ss += p;
  }
  if (lane < 8){ marr[n*NH+lane] = vmax; sarr[n*NH+lane] = ss; }
}

// ---------------- GAT: weighted aggregation + bias + relu -> h2 (f32) ----------------
__global__ __launch_bounds__(256) void k_gat_agg(const float* __restrict__ gfeat,
    const u32* __restrict__ col, const u32* __restrict__ start, const u32* __restrict__ cnt,
    const float* __restrict__ a_src, const float* __restrict__ a_dst,
    const float* __restrict__ marr, const float* __restrict__ sarr,
    const float* __restrict__ b_att, float* __restrict__ h2){
  const int n = (int)((blockIdx.x*blockDim.x + threadIdx.x) >> 6);
  if (n >= NN) return;
  const int lane = threadIdx.x & 63;
  const int head = lane >> 3;          // feature block lane*4 -> head = lane*4/32
  const int fo = lane*4;
  const u32 b = start[n], e = b + cnt[n];
  const float mh = marr[n*NH+head];
  const float inv_s = 1.f / sarr[n*NH+head];
  const float ad = a_dst[n*NH+head];
  float a0=0.f,a1=0.f,a2=0.f,a3=0.f;
  for (u32 k=b; k<e; ++k){
    const u32 s = col[k];
    const float alpha = expf(leakyf(a_src[s*NH+head] + ad) - mh) * inv_s;
    const float4 v = *(const float4*)(gfeat + (size_t)s*HID + fo);
    a0 = fmaf(alpha, v.x, a0);
    a1 = fmaf(alpha, v.y, a1);
    a2 = fmaf(alpha, v.z, a2);
    a3 = fmaf(alpha, v.w, a3);
  }
  const float4 bv = *(const float4*)(b_att + fo);
  *(float4*)(h2 + (size_t)n*HID + fo) = make_float4(
      fmaxf(a0 + bv.x, 0.f), fmaxf(a1 + bv.y, 0.f),
      fmaxf(a2 + bv.z, 0.f), fmaxf(a3 + bv.w, 0.f));
}

extern "C" void kernel_launch(void* const* d_in, const int* in_sizes, int n_in,
                              void* d_out, int out_size, void* d_ws, size_t ws_size,
                              hipStream_t stream){
  const float* x    = (const float*)d_in[0];
  const int*   ei   = (const int*)d_in[1];
  const float* w1   = (const float*)d_in[2];
  const float* b1   = (const float*)d_in[3];
  const float* watt = (const float*)d_in[4];
  const float* atts = (const float*)d_in[5];
  const float* attd = (const float*)d_in[6];
  const float* batt = (const float*)d_in[7];
  const float* wmu  = (const float*)d_in[8];
  const float* bmu  = (const float*)d_in[9];
  const float* wls  = (const float*)d_in[10];
  const float* bls  = (const float*)d_in[11];
  const int* esrc = ei;
  const int* edst = ei + EE;

  char* p = (char*)d_ws;
  float* bufA = (float*)p;  p += (size_t)NN*HID*4;   // 51.2 MB: aggX -> g -> aggH2
  float* bufB = (float*)p;  p += (size_t)NN*HID*4;   // 51.2 MB: h1 -> h2
  bf16* w1hi  = (bf16*)p;   p += (size_t)HID*HID*2;
  bf16* w1lo  = (bf16*)p;   p += (size_t)HID*HID*2;
  bf16* wahi  = (bf16*)p;   p += (size_t)HID*HID*2;
  bf16* walo  = (bf16*)p;   p += (size_t)HID*HID*2;
  bf16* wmhi  = (bf16*)p;   p += (size_t)HID*OC*2;
  bf16* wmlo  = (bf16*)p;   p += (size_t)HID*OC*2;
  bf16* wlhi  = (bf16*)p;   p += (size_t)HID*OC*2;
  bf16* wllo  = (bf16*)p;   p += (size_t)HID*OC*2;
  float* dinv = (float*)p;  p += (size_t)NN*4;
  float* asr  = (float*)p;  p += (size_t)NN*NH*4;
  float* ads  = (float*)p;  p += (size_t)NN*NH*4;
  float* marr = (float*)p;  p += (size_t)NN*NH*4;
  float* sarr = (float*)p;  p += (size_t)NN*NH*4;
  u32*   cnt  = (u32*)p;    p += (size_t)NN*4;
  u32*   start= (u32*)p;    p += (size_t)NN*4;
  u32*   pos  = (u32*)p;    p += (size_t)NN*4;
  u32*   col  = (u32*)p;    p += (size_t)ET*4;
  u32*   counter = (u32*)p; p += 256;

  const int TB = 256;
  // CSR build (bucket order arbitrary -> no prefix scan needed)
  k_init <<<(NN+TB-1)/TB, TB, 0, stream>>>(cnt, counter);
  k_count<<<(EE+TB-1)/TB, TB, 0, stream>>>(edst, cnt);
  k_alloc<<<(NN+TB-1)/TB, TB, 0, stream>>>(cnt, counter, start, pos);
  k_fill <<<(ET+TB-1)/TB, TB, 0, stream>>>(esrc, edst, pos, col);
  k_dinv <<<(NN+TB-1)/TB, TB, 0, stream>>>(cnt, dinv);
  // weight splits (tiny)
  k_wsplit<HID><<<(HID*HID+TB-1)/TB, TB, 0, stream>>>(w1,  w1hi, w1lo);
  k_wsplit<HID><<<(HID*HID+TB-1)/TB, TB, 0, stream>>>(watt, wahi, walo);
  k_wsplit<OC> <<<(OC*HID+TB-1)/TB, TB, 0, stream>>>(wmu, wmhi, wmlo);
  k_wsplit<OC> <<<(OC*HID+TB-1)/TB, TB, 0, stream>>>(wls, wlhi, wllo);

  const int NWB = NN/4;   // 12500 blocks, 1 wave per node
  // layer 1: h1 = gelu(agg(x) @ w1 + b1)
  k_agg<<<NWB, TB, 0, stream>>>(x, col, start, cnt, dinv, bufA);
  k_gemm<HID,4,1><<<NN/16, TB, 0, stream>>>(bufA, w1hi, w1lo, b1, bufB);
  // GAT: g = h1 @ w_att ; attention ; h2 = relu(agg_att(g) + b_att)
  k_gemm<HID,4,0><<<NN/16, TB, 0, stream>>>(bufB, wahi, walo, nullptr, bufA);
  k_attcoef<<<NWB, TB, 0, stream>>>(bufA, atts, attd, asr, ads);
  k_gat_ms <<<NWB, TB, 0, stream>>>(col, start, cnt, asr, ads, marr, sarr);
  k_gat_agg<<<NWB, TB, 0, stream>>>(bufA, col, start, cnt, asr, ads, marr, sarr, batt, bufB);
  // layer 3: one shared aggregation, two small GEMMs
  k_agg<<<NWB, TB, 0, stream>>>(bufB, col, start, cnt, dinv, bufA);
  float* out = (float*)d_out;
  k_gemm<OC,1,0><<<NN/16, TB, 0, stream>>>(bufA, wmhi, wmlo, bmu, out);
  k_gemm<OC,1,0><<<NN/16, TB, 0, stream>>>(bufA, wlhi, wllo, bls, out + (size_t)NN*OC);
}

// Round 3
// 729.908 us; speedup vs baseline: 1.2198x; 1.2198x over previous
//
#include <hip/hip_runtime.h>

#define NN 50000
#define EE 800000
#define ET (EE + NN)
#define HID 256
#define NH 8
#define HC 32
#define OC 64
#define PC 128   // layer-3 projected width (mu||logstd)

typedef unsigned int u32;
typedef __bf16 bf16;
typedef _Float16 f16;
typedef __attribute__((ext_vector_type(8))) __bf16 bf16x8;
typedef __attribute__((ext_vector_type(8))) _Float16 f16x8;
typedef __attribute__((ext_vector_type(4))) _Float16 f16x4;
typedef __attribute__((ext_vector_type(2))) _Float16 f16x2;
typedef __attribute__((ext_vector_type(4))) float f32x4;

static __device__ __forceinline__ float geluf(float x){
  float t = tanhf(0.7978845608028654f*(x + 0.044715f*x*x*x));
  return 0.5f*x*(1.0f+t);
}
static __device__ __forceinline__ float leakyf(float x){
  return x > 0.0f ? x : 0.2f*x;
}

// ---------------- CSR build ----------------
__global__ void k_init(u32* cnt, u32* counter){
  int i = blockIdx.x*blockDim.x + threadIdx.x;
  if (i < NN) cnt[i] = 1u;            // self loop
  if (i == 0) counter[0] = 0u;
}
__global__ void k_count(const int* __restrict__ dst, u32* __restrict__ cnt){
  int e = blockIdx.x*blockDim.x + threadIdx.x;
  if (e < EE) atomicAdd(&cnt[dst[e]], 1u);
}
__global__ void k_alloc(const u32* __restrict__ cnt, u32* counter,
                        u32* __restrict__ start, u32* __restrict__ pos){
  int n = blockIdx.x*blockDim.x + threadIdx.x;
  if (n < NN){ u32 s = atomicAdd(counter, cnt[n]); start[n] = s; pos[n] = s; }
}
__global__ void k_fill(const int* __restrict__ src, const int* __restrict__ dst,
                       u32* __restrict__ pos, u32* __restrict__ col){
  int e = blockIdx.x*blockDim.x + threadIdx.x;
  if (e < ET){
    int s, d;
    if (e < EE){ s = src[e]; d = dst[e]; } else { s = d = e - EE; }
    u32 idx = atomicAdd(&pos[d], 1u);
    col[idx] = (u32)s;
  }
}
__global__ void k_dinv(const u32* __restrict__ cnt, float* __restrict__ dinv){
  int n = blockIdx.x*blockDim.x + threadIdx.x;
  if (n < NN) dinv[n] = rsqrtf((float)cnt[n]);
}

// ---------------- weight splits ----------------
// W[K=256][NC] f32 row-major -> hi/lo bf16 col-major [c][k]
template<int NC>
__global__ void k_wsplit_bf(const float* __restrict__ W, bf16* __restrict__ Whi, bf16* __restrict__ Wlo){
  int e = blockIdx.x*blockDim.x + threadIdx.x;
  if (e >= NC*HID) return;
  int c = e / HID, k = e % HID;
  float w = W[(size_t)k*NC + c];
  bf16 hi = (bf16)w;
  bf16 lo = (bf16)(w - (float)hi);
  Whi[(size_t)c*HID + k] = hi;
  Wlo[(size_t)c*HID + k] = lo;
}
// W[K=256][NC] f32 row-major -> hi/lo f16 col-major [coff+c][k]
template<int NC>
__global__ void k_wsplit_f16(const float* __restrict__ W, f16* __restrict__ Whi, f16* __restrict__ Wlo, int coff){
  int e = blockIdx.x*blockDim.x + threadIdx.x;
  if (e >= NC*HID) return;
  int c = e / HID, k = e % HID;
  float w = W[(size_t)k*NC + c];
  f16 hi = (f16)w;
  f16 lo = (f16)(w - (float)hi);
  Whi[(size_t)(c+coff)*HID + k] = hi;
  Wlo[(size_t)(c+coff)*HID + k] = lo;
}

// ---------------- GEMM (f32 A, 3-pass bf16): C[M,NC] = A[M,256] @ W, f16 out ----------------
template<int NC, int NF>
__global__ __launch_bounds__(256) void k_gemm_f32A(const float* __restrict__ A,
    const bf16* __restrict__ Whi, const bf16* __restrict__ Wlo, f16* __restrict__ Cout){
  const int tid = threadIdx.x;
  const int w = tid >> 6, lane = tid & 63;
  const int r = lane & 15, g = lane >> 4;
  const int bm = blockIdx.x;
  const int grow = bm*16 + r;
  const int wcol = w * (NF*16);
  f32x4 acc[NF];
  #pragma unroll
  for (int j=0;j<NF;++j){ f32x4 z = {0.f,0.f,0.f,0.f}; acc[j] = z; }
  #pragma unroll
  for (int kk=0; kk<8; ++kk){
    const int k0 = kk*32 + g*8;
    const float* ap = A + (size_t)grow*HID + k0;
    const float4 u0 = *(const float4*)ap;
    const float4 u1 = *(const float4*)(ap+4);
    float af[8] = {u0.x,u0.y,u0.z,u0.w,u1.x,u1.y,u1.z,u1.w};
    bf16x8 ahi, alo;
    #pragma unroll
    for (int i=0;i<8;++i){
      bf16 h = (bf16)af[i];
      ahi[i] = h;
      alo[i] = (bf16)(af[i] - (float)h);
    }
    #pragma unroll
    for (int j=0;j<NF;++j){
      const int c = wcol + j*16 + r;
      const size_t off = (size_t)c*HID + k0;
      const bf16x8 wh = *(const bf16x8*)(Whi + off);
      const bf16x8 wl = *(const bf16x8*)(Wlo + off);
      acc[j] = __builtin_amdgcn_mfma_f32_16x16x32_bf16(ahi, wh, acc[j], 0, 0, 0);
      acc[j] = __builtin_amdgcn_mfma_f32_16x16x32_bf16(ahi, wl, acc[j], 0, 0, 0);
      acc[j] = __builtin_amdgcn_mfma_f32_16x16x32_bf16(alo, wh, acc[j], 0, 0, 0);
    }
  }
  #pragma unroll
  for (int j=0;j<NF;++j){
    const int c = wcol + j*16 + r;
    #pragma unroll
    for (int q=0;q<4;++q){
      const int row = bm*16 + g*4 + q;
      Cout[(size_t)row*NC + c] = (f16)acc[j][q];
    }
  }
}

// ---------------- GEMM (f16 A, 2-pass f16 W split): C[M,NC] = A[M,256] @ W, f16 out ----------------
template<int NC, int NF>
__global__ __launch_bounds__(256) void k_gemm_f16A(const f16* __restrict__ A,
    const f16* __restrict__ Whi, const f16* __restrict__ Wlo, f16* __restrict__ Cout){
  const int tid = threadIdx.x;
  const int w = tid >> 6, lane = tid & 63;
  const int r = lane & 15, g = lane >> 4;
  const int bm = blockIdx.x;
  const int grow = bm*16 + r;
  const int wcol = w * (NF*16);
  f32x4 acc[NF];
  #pragma unroll
  for (int j=0;j<NF;++j){ f32x4 z = {0.f,0.f,0.f,0.f}; acc[j] = z; }
  #pragma unroll
  for (int kk=0; kk<8; ++kk){
    const int k0 = kk*32 + g*8;
    const f16x8 a = *(const f16x8*)(A + (size_t)grow*HID + k0);
    #pragma unroll
    for (int j=0;j<NF;++j){
      const int c = wcol + j*16 + r;
      const size_t off = (size_t)c*HID + k0;
      const f16x8 wh = *(const f16x8*)(Whi + off);
      const f16x8 wl = *(const f16x8*)(Wlo + off);
      acc[j] = __builtin_amdgcn_mfma_f32_16x16x32_f16(a, wh, acc[j], 0, 0, 0);
      acc[j] = __builtin_amdgcn_mfma_f32_16x16x32_f16(a, wl, acc[j], 0, 0, 0);
    }
  }
  #pragma unroll
  for (int j=0;j<NF;++j){
    const int c = wcol + j*16 + r;
    #pragma unroll
    for (int q=0;q<4;++q){
      const int row = bm*16 + g*4 + q;
      Cout[(size_t)row*NC + c] = (f16)acc[j][q];
    }
  }
}

// ---------------- layer-1 agg: wave/node, fp16 256-dim gather, +bias, gelu -> f16 ----------------
__global__ __launch_bounds__(256) void k_aggH(const f16* __restrict__ feat,
    const u32* __restrict__ col, const u32* __restrict__ start, const u32* __restrict__ cnt,
    const float* __restrict__ dinv, const float* __restrict__ bias, f16* __restrict__ out){
  const int n = (int)((blockIdx.x*blockDim.x + threadIdx.x) >> 6);
  if (n >= NN) return;
  const int lane = threadIdx.x & 63;
  const u32 b = start[n], e = b + cnt[n];
  const float dd = dinv[n];
  const int fo = lane*4;
  float a0=0.f,a1=0.f,a2=0.f,a3=0.f;
  for (u32 k=b; k<e; ++k){
    const u32 s = col[k];
    const float nrm = dd * dinv[s];
    const f16x4 v = *(const f16x4*)(feat + (size_t)s*HID + fo);
    a0 = fmaf(nrm, (float)v.x, a0);
    a1 = fmaf(nrm, (float)v.y, a1);
    a2 = fmaf(nrm, (float)v.z, a2);
    a3 = fmaf(nrm, (float)v.w, a3);
  }
  const float4 bv = *(const float4*)(bias + fo);
  f16x4 o;
  o.x = (f16)geluf(a0 + bv.x);
  o.y = (f16)geluf(a1 + bv.y);
  o.z = (f16)geluf(a2 + bv.z);
  o.w = (f16)geluf(a3 + bv.w);
  *(f16x4*)(out + (size_t)n*HID + fo) = o;
}

// ---------------- GAT: per-node attention coefficients (fp16 feats) ----------------
__global__ __launch_bounds__(256) void k_attcoef(const f16* __restrict__ gfeat,
    const float* __restrict__ atts, const float* __restrict__ attd,
    float* __restrict__ a_src, float* __restrict__ a_dst){
  const int n = (int)((blockIdx.x*blockDim.x + threadIdx.x) >> 6);
  if (n >= NN) return;
  const int lane = threadIdx.x & 63;
  const int head = lane >> 3, sub = lane & 7;
  const int off = head*HC + sub*4;
  const f16x4 gv = *(const f16x4*)(gfeat + (size_t)n*HID + off);
  const float4 sv = *(const float4*)(atts + off);
  const float4 dv = *(const float4*)(attd + off);
  const float g0=(float)gv.x, g1=(float)gv.y, g2=(float)gv.z, g3=(float)gv.w;
  float ps = g0*sv.x + g1*sv.y + g2*sv.z + g3*sv.w;
  float pd = g0*dv.x + g1*dv.y + g2*dv.z + g3*dv.w;
  ps += __shfl_xor(ps,1); ps += __shfl_xor(ps,2); ps += __shfl_xor(ps,4);
  pd += __shfl_xor(pd,1); pd += __shfl_xor(pd,2); pd += __shfl_xor(pd,4);
  if (sub == 0){ a_src[n*NH+head] = ps; a_dst[n*NH+head] = pd; }
}

// ---------------- GAT: segment max + sum (wave per node, 8 edges x 8 heads) ----------------
__global__ __launch_bounds__(256) void k_gat_ms(const u32* __restrict__ col,
    const u32* __restrict__ start, const u32* __restrict__ cnt,
    const float* __restrict__ a_src, const float* __restrict__ a_dst,
    float* __restrict__ marr, float* __restrict__ sarr){
  const int n = (int)((blockIdx.x*blockDim.x + threadIdx.x) >> 6);
  if (n >= NN) return;
  const int lane = threadIdx.x & 63;
  const int h = lane & 7, e8 = lane >> 3;
  const u32 b = start[n], c = cnt[n];
  const float ad = a_dst[n*NH+h];
  float vmax = -1e30f;
  for (u32 k0=0; k0<c; k0+=8){
    const u32 ke = k0 + (u32)e8;
    float l = -1e30f;
    if (ke < c){
      const u32 s = col[b+ke];
      l = leakyf(a_src[s*NH+h] + ad);
    }
    l = fmaxf(l, __shfl_xor(l,8));
    l = fmaxf(l, __shfl_xor(l,16));
    l = fmaxf(l, __shfl_xor(l,32));
    vmax = fmaxf(vmax, l);
  }
  float ss = 0.f;
  for (u32 k0=0; k0<c; k0+=8){
    const u32 ke = k0 + (u32)e8;
    float p = 0.f;
    if (ke < c){
      const u32 s = col[b+ke];
      p = expf(leakyf(a_src[s*NH+h] + ad) - vmax);
    }
    p += __shfl_xor(p,8); p += __shfl_xor(p,16); p += __shfl_xor(p,32);
    ss += p;
  }
  if (lane < 8){ marr[n*NH+lane] = vmax; sarr[n*NH+lane] = ss; }
}

// ---------------- GAT: weighted aggregation + bias + relu -> h2 (f16) ----------------
__global__ __launch_bounds__(256) void k_gat_agg(const f16* __restrict__ gfeat,
    const u32* __restrict__ col, const u32* __restrict__ start, const u32* __restrict__ cnt,
    const float* __restrict__ a_src, const float* __restrict__ a_dst,
    const float* __restrict__ marr, const float* __restrict__ sarr,
    const float* __restrict__ b_att, f16* __restrict__ h2){
  const int n = (int)((blockIdx.x*blockDim.x + threadIdx.x) >> 6);
  if (n >= NN) return;
  const int lane = threadIdx.x & 63;
  const int head = lane >> 3;          // feats lane*4 -> head = lane*4/32
  const int fo = lane*4;
  const u32 b = start[n], e = b + cnt[n];
  const float mh = marr[n*NH+head];
  const float inv_s = 1.f / sarr[n*NH+head];
  const float ad = a_dst[n*NH+head];
  float a0=0.f,a1=0.f,a2=0.f,a3=0.f;
  for (u32 k=b; k<e; ++k){
    const u32 s = col[k];
    const float alpha = expf(leakyf(a_src[s*NH+head] + ad) - mh) * inv_s;
    const f16x4 v = *(const f16x4*)(gfeat + (size_t)s*HID + fo);
    a0 = fmaf(alpha, (float)v.x, a0);
    a1 = fmaf(alpha, (float)v.y, a1);
    a2 = fmaf(alpha, (float)v.z, a2);
    a3 = fmaf(alpha, (float)v.w, a3);
  }
  const float4 bv = *(const float4*)(b_att + fo);
  f16x4 o;
  o.x = (f16)fmaxf(a0 + bv.x, 0.f);
  o.y = (f16)fmaxf(a1 + bv.y, 0.f);
  o.z = (f16)fmaxf(a2 + bv.z, 0.f);
  o.w = (f16)fmaxf(a3 + bv.w, 0.f);
  *(f16x4*)(h2 + (size_t)n*HID + fo) = o;
}

// ---------------- layer-3 agg: fp16 128-dim gather, +bias, f32 out (mu | logstd) ----------------
__global__ __launch_bounds__(256) void k_agg_out(const f16* __restrict__ p,
    const u32* __restrict__ col, const u32* __restrict__ start, const u32* __restrict__ cnt,
    const float* __restrict__ dinv, const float* __restrict__ b_mu, const float* __restrict__ b_ls,
    float* __restrict__ out){
  const int n = (int)((blockIdx.x*blockDim.x + threadIdx.x) >> 6);
  if (n >= NN) return;
  const int lane = threadIdx.x & 63;
  const u32 b = start[n], e = b + cnt[n];
  const float dd = dinv[n];
  const int fo = lane*2;
  float a0=0.f, a1=0.f;
  for (u32 k=b; k<e; ++k){
    const u32 s = col[k];
    const float nrm = dd * dinv[s];
    const f16x2 v = *(const f16x2*)(p + (size_t)s*PC + fo);
    a0 = fmaf(nrm, (float)v.x, a0);
    a1 = fmaf(nrm, (float)v.y, a1);
  }
  if (lane < 32){
    const int c = fo;                      // 0..62
    float2 o = make_float2(a0 + b_mu[c], a1 + b_mu[c+1]);
    *(float2*)(out + (size_t)n*OC + c) = o;
  } else {
    const int c = fo - OC;                 // 0..62
    float2 o = make_float2(a0 + b_ls[c], a1 + b_ls[c+1]);
    *(float2*)(out + (size_t)NN*OC + (size_t)n*OC + c) = o;
  }
}

extern "C" void kernel_launch(void* const* d_in, const int* in_sizes, int n_in,
                              void* d_out, int out_size, void* d_ws, size_t ws_size,
                              hipStream_t stream){
  const float* x    = (const float*)d_in[0];
  const int*   ei   = (const int*)d_in[1];
  const float* w1   = (const float*)d_in[2];
  const float* b1   = (const float*)d_in[3];
  const float* watt = (const float*)d_in[4];
  const float* atts = (const float*)d_in[5];
  const float* attd = (const float*)d_in[6];
  const float* batt = (const float*)d_in[7];
  const float* wmu  = (const float*)d_in[8];
  const float* bmu  = (const float*)d_in[9];
  const float* wls  = (const float*)d_in[10];
  const float* bls  = (const float*)d_in[11];
  const int* esrc = ei;
  const int* edst = ei + EE;

  char* p = (char*)d_ws;
  f16* bufA = (f16*)p;  p += (size_t)NN*HID*2;   // 25.6 MB: g1 (x@w1) -> h2
  f16* bufB = (f16*)p;  p += (size_t)NN*HID*2;   // 25.6 MB: h1 -> proj(128)
  f16* bufC = (f16*)p;  p += (size_t)NN*HID*2;   // 25.6 MB: g (GAT feats)
  bf16* w1hi = (bf16*)p; p += (size_t)HID*HID*2;
  bf16* w1lo = (bf16*)p; p += (size_t)HID*HID*2;
  f16* wahi  = (f16*)p;  p += (size_t)HID*HID*2;
  f16* walo  = (f16*)p;  p += (size_t)HID*HID*2;
  f16* wchi  = (f16*)p;  p += (size_t)PC*HID*2;
  f16* wclo  = (f16*)p;  p += (size_t)PC*HID*2;
  float* dinv = (float*)p; p += (size_t)NN*4;
  float* asr  = (float*)p; p += (size_t)NN*NH*4;
  float* ads  = (float*)p; p += (size_t)NN*NH*4;
  float* marr = (float*)p; p += (size_t)NN*NH*4;
  float* sarr = (float*)p; p += (size_t)NN*NH*4;
  u32*   cnt  = (u32*)p;   p += (size_t)NN*4;
  u32*   start= (u32*)p;   p += (size_t)NN*4;
  u32*   pos  = (u32*)p;   p += (size_t)NN*4;
  u32*   col  = (u32*)p;   p += (size_t)ET*4;
  u32*   counter = (u32*)p; p += 256;

  const int TB = 256;
  // CSR build (bucket order arbitrary -> no prefix scan needed)
  k_init <<<(NN+TB-1)/TB, TB, 0, stream>>>(cnt, counter);
  k_count<<<(EE+TB-1)/TB, TB, 0, stream>>>(edst, cnt);
  k_alloc<<<(NN+TB-1)/TB, TB, 0, stream>>>(cnt, counter, start, pos);
  k_fill <<<(ET+TB-1)/TB, TB, 0, stream>>>(esrc, edst, pos, col);
  k_dinv <<<(NN+TB-1)/TB, TB, 0, stream>>>(cnt, dinv);
  // weight splits (tiny)
  k_wsplit_bf<HID><<<(HID*HID+TB-1)/TB, TB, 0, stream>>>(w1, w1hi, w1lo);
  k_wsplit_f16<HID><<<(HID*HID+TB-1)/TB, TB, 0, stream>>>(watt, wahi, walo, 0);
  k_wsplit_f16<OC> <<<(OC*HID+TB-1)/TB, TB, 0, stream>>>(wmu, wchi, wclo, 0);
  k_wsplit_f16<OC> <<<(OC*HID+TB-1)/TB, TB, 0, stream>>>(wls, wchi, wclo, OC);

  const int NWB = NN/4;   // 12500 blocks, 1 wave per node
  // layer 1: g1 = x@w1 ; h1 = gelu(agg(g1) + b1)
  k_gemm_f32A<HID,4><<<NN/16, TB, 0, stream>>>(x, w1hi, w1lo, bufA);
  k_aggH<<<NWB, TB, 0, stream>>>(bufA, col, start, cnt, dinv, b1, bufB);
  // GAT: g = h1@w_att ; attention ; h2 = relu(agg_att(g) + b_att)
  k_gemm_f16A<HID,4><<<NN/16, TB, 0, stream>>>(bufB, wahi, walo, bufC);
  k_attcoef<<<NWB, TB, 0, stream>>>(bufC, atts, attd, asr, ads);
  k_gat_ms <<<NWB, TB, 0, stream>>>(col, start, cnt, asr, ads, marr, sarr);
  k_gat_agg<<<NWB, TB, 0, stream>>>(bufC, col, start, cnt, asr, ads, marr, sarr, batt, bufA);
  // layer 3: project first (128 cols = mu||ls), then one 128-dim gather -> d_out
  k_gemm_f16A<PC,2><<<NN/16, TB, 0, stream>>>(bufA, wchi, wclo, bufB);
  k_agg_out<<<NWB, TB, 0, stream>>>(bufB, col, start, cnt, dinv, bmu, bls, (float*)d_out);
}

// Round 4
// 498.042 us; speedup vs baseline: 1.7877x; 1.4656x over previous
//
#include <hip/hip_runtime.h>

#define NN 50000
#define EE 800000
#define ET (EE + NN)
#define HID 256
#define NH 8
#define HC 32
#define OC 64
#define PC 128   // layer-3 projected width (mu||logstd)

typedef unsigned int u32;
typedef __bf16 bf16;
typedef _Float16 f16;
typedef __attribute__((ext_vector_type(8))) __bf16 bf16x8;
typedef __attribute__((ext_vector_type(8))) _Float16 f16x8;
typedef __attribute__((ext_vector_type(4))) _Float16 f16x4;
typedef __attribute__((ext_vector_type(2))) _Float16 f16x2;
typedef __attribute__((ext_vector_type(4))) float f32x4;

static __device__ __forceinline__ float geluf(float x){
  float t = tanhf(0.7978845608028654f*(x + 0.044715f*x*x*x));
  return 0.5f*x*(1.0f+t);
}
static __device__ __forceinline__ float leakyf(float x){
  return x > 0.0f ? x : 0.2f*x;
}

// ---------------- CSR build ----------------
__global__ void k_init(u32* cnt, u32* counter){
  int i = blockIdx.x*blockDim.x + threadIdx.x;
  if (i < NN) cnt[i] = 1u;            // self loop
  if (i == 0) counter[0] = 0u;
}
__global__ void k_count(const int* __restrict__ dst, u32* __restrict__ cnt){
  int e = blockIdx.x*blockDim.x + threadIdx.x;
  if (e < EE) atomicAdd(&cnt[dst[e]], 1u);
}
__global__ void k_alloc(const u32* __restrict__ cnt, u32* counter,
                        u32* __restrict__ start, u32* __restrict__ pos,
                        float* __restrict__ dinv){
  int n = blockIdx.x*blockDim.x + threadIdx.x;
  if (n < NN){
    u32 c = cnt[n];
    u32 s = atomicAdd(counter, c);
    start[n] = s; pos[n] = s;
    dinv[n] = rsqrtf((float)c);
  }
}
__global__ void k_fill(const int* __restrict__ src, const int* __restrict__ dst,
                       u32* __restrict__ pos, u32* __restrict__ col){
  int e = blockIdx.x*blockDim.x + threadIdx.x;
  if (e < ET){
    int s, d;
    if (e < EE){ s = src[e]; d = dst[e]; } else { s = d = e - EE; }
    u32 idx = atomicAdd(&pos[d], 1u);
    col[idx] = (u32)s;
  }
}

// ---------------- weight splits ----------------
template<int NC>
__global__ void k_wsplit_bf(const float* __restrict__ W, bf16* __restrict__ Whi, bf16* __restrict__ Wlo){
  int e = blockIdx.x*blockDim.x + threadIdx.x;
  if (e >= NC*HID) return;
  int c = e / HID, k = e % HID;
  float w = W[(size_t)k*NC + c];
  bf16 hi = (bf16)w;
  bf16 lo = (bf16)(w - (float)hi);
  Whi[(size_t)c*HID + k] = hi;
  Wlo[(size_t)c*HID + k] = lo;
}
template<int NC>
__global__ void k_wsplit_f16(const float* __restrict__ W, f16* __restrict__ Whi, f16* __restrict__ Wlo, int coff){
  int e = blockIdx.x*blockDim.x + threadIdx.x;
  if (e >= NC*HID) return;
  int c = e / HID, k = e % HID;
  float w = W[(size_t)k*NC + c];
  f16 hi = (f16)w;
  f16 lo = (f16)(w - (float)hi);
  Whi[(size_t)(c+coff)*HID + k] = hi;
  Wlo[(size_t)(c+coff)*HID + k] = lo;
}

// ---------------- GEMM (f32 A, 3-pass bf16, MR row-replication) ----------------
// block = 4 waves; rows = MR*16 per block (shared); wave w covers cols [w*NF*16, ...)
template<int NC, int NF, int MR>
__global__ __launch_bounds__(256) void k_gemm_f32A(const float* __restrict__ A,
    const bf16* __restrict__ Whi, const bf16* __restrict__ Wlo, f16* __restrict__ Cout){
  const int tid = threadIdx.x;
  const int w = tid >> 6, lane = tid & 63;
  const int r = lane & 15, g = lane >> 4;
  const int row0 = blockIdx.x * (MR*16);
  const int wcol = w * (NF*16);
  f32x4 acc[MR][NF];
  #pragma unroll
  for (int m=0;m<MR;++m)
    #pragma unroll
    for (int j=0;j<NF;++j){ f32x4 z = {0.f,0.f,0.f,0.f}; acc[m][j] = z; }
  #pragma unroll
  for (int kk=0; kk<8; ++kk){
    const int k0 = kk*32 + g*8;
    bf16x8 ahi[MR], alo[MR];
    #pragma unroll
    for (int m=0;m<MR;++m){
      const int row = row0 + m*16 + r;
      float af[8] = {0.f,0.f,0.f,0.f,0.f,0.f,0.f,0.f};
      if (row < NN){
        const float* ap = A + (size_t)row*HID + k0;
        const float4 u0 = *(const float4*)ap;
        const float4 u1 = *(const float4*)(ap+4);
        af[0]=u0.x; af[1]=u0.y; af[2]=u0.z; af[3]=u0.w;
        af[4]=u1.x; af[5]=u1.y; af[6]=u1.z; af[7]=u1.w;
      }
      #pragma unroll
      for (int i=0;i<8;++i){
        bf16 h = (bf16)af[i];
        ahi[m][i] = h;
        alo[m][i] = (bf16)(af[i] - (float)h);
      }
    }
    #pragma unroll
    for (int j=0;j<NF;++j){
      const int c = wcol + j*16 + r;
      const size_t off = (size_t)c*HID + k0;
      const bf16x8 wh = *(const bf16x8*)(Whi + off);
      const bf16x8 wl = *(const bf16x8*)(Wlo + off);
      #pragma unroll
      for (int m=0;m<MR;++m){
        acc[m][j] = __builtin_amdgcn_mfma_f32_16x16x32_bf16(ahi[m], wh, acc[m][j], 0, 0, 0);
        acc[m][j] = __builtin_amdgcn_mfma_f32_16x16x32_bf16(ahi[m], wl, acc[m][j], 0, 0, 0);
        acc[m][j] = __builtin_amdgcn_mfma_f32_16x16x32_bf16(alo[m], wh, acc[m][j], 0, 0, 0);
      }
    }
  }
  #pragma unroll
  for (int j=0;j<NF;++j){
    const int c = wcol + j*16 + r;
    #pragma unroll
    for (int m=0;m<MR;++m){
      #pragma unroll
      for (int q=0;q<4;++q){
        const int row = row0 + m*16 + g*4 + q;
        if (row < NN) Cout[(size_t)row*NC + c] = (f16)acc[m][j][q];
      }
    }
  }
}

// ---------------- GEMM (f16 A, 2-pass f16 W split, MR row-replication) ----------------
template<int NC, int NF, int MR>
__global__ __launch_bounds__(256) void k_gemm_f16A(const f16* __restrict__ A,
    const f16* __restrict__ Whi, const f16* __restrict__ Wlo, f16* __restrict__ Cout){
  const int tid = threadIdx.x;
  const int w = tid >> 6, lane = tid & 63;
  const int r = lane & 15, g = lane >> 4;
  const int row0 = blockIdx.x * (MR*16);
  const int wcol = w * (NF*16);
  f32x4 acc[MR][NF];
  #pragma unroll
  for (int m=0;m<MR;++m)
    #pragma unroll
    for (int j=0;j<NF;++j){ f32x4 z = {0.f,0.f,0.f,0.f}; acc[m][j] = z; }
  #pragma unroll
  for (int kk=0; kk<8; ++kk){
    const int k0 = kk*32 + g*8;
    f16x8 a[MR];
    #pragma unroll
    for (int m=0;m<MR;++m){
      const int row = row0 + m*16 + r;
      f16x8 z = {0,0,0,0,0,0,0,0};
      a[m] = (row < NN) ? *(const f16x8*)(A + (size_t)row*HID + k0) : z;
    }
    #pragma unroll
    for (int j=0;j<NF;++j){
      const int c = wcol + j*16 + r;
      const size_t off = (size_t)c*HID + k0;
      const f16x8 wh = *(const f16x8*)(Whi + off);
      const f16x8 wl = *(const f16x8*)(Wlo + off);
      #pragma unroll
      for (int m=0;m<MR;++m){
        acc[m][j] = __builtin_amdgcn_mfma_f32_16x16x32_f16(a[m], wh, acc[m][j], 0, 0, 0);
        acc[m][j] = __builtin_amdgcn_mfma_f32_16x16x32_f16(a[m], wl, acc[m][j], 0, 0, 0);
      }
    }
  }
  #pragma unroll
  for (int j=0;j<NF;++j){
    const int c = wcol + j*16 + r;
    #pragma unroll
    for (int m=0;m<MR;++m){
      #pragma unroll
      for (int q=0;q<4;++q){
        const int row = row0 + m*16 + g*4 + q;
        if (row < NN) Cout[(size_t)row*NC + c] = (f16)acc[m][j][q];
      }
    }
  }
}

// ---------------- layer-1 agg: wave/node, fp16 256-dim gather, +bias, gelu -> f16 ----------------
__global__ __launch_bounds__(256) void k_aggH(const f16* __restrict__ feat,
    const u32* __restrict__ col, const u32* __restrict__ start, const u32* __restrict__ cnt,
    const float* __restrict__ dinv, const float* __restrict__ bias, f16* __restrict__ out){
  const int n = (int)((blockIdx.x*blockDim.x + threadIdx.x) >> 6);
  if (n >= NN) return;
  const int lane = threadIdx.x & 63;
  const u32 b = start[n], e = b + cnt[n];
  const float dd = dinv[n];
  const int fo = lane*4;
  float a0=0.f,a1=0.f,a2=0.f,a3=0.f;
  // depth-2 software pipeline
  u32 s0 = col[b];
  float di0 = dinv[s0];
  f16x4 v0 = *(const f16x4*)(feat + (size_t)s0*HID + fo);
  for (u32 k=b+1; k<e; ++k){
    const u32 s1 = col[k];
    const float di1 = dinv[s1];
    const f16x4 v1 = *(const f16x4*)(feat + (size_t)s1*HID + fo);
    const float nrm = dd * di0;
    a0 = fmaf(nrm, (float)v0.x, a0);
    a1 = fmaf(nrm, (float)v0.y, a1);
    a2 = fmaf(nrm, (float)v0.z, a2);
    a3 = fmaf(nrm, (float)v0.w, a3);
    v0 = v1; di0 = di1;
  }
  const float nrm = dd * di0;
  a0 = fmaf(nrm, (float)v0.x, a0);
  a1 = fmaf(nrm, (float)v0.y, a1);
  a2 = fmaf(nrm, (float)v0.z, a2);
  a3 = fmaf(nrm, (float)v0.w, a3);
  const float4 bv = *(const float4*)(bias + fo);
  f16x4 o;
  o.x = (f16)geluf(a0 + bv.x);
  o.y = (f16)geluf(a1 + bv.y);
  o.z = (f16)geluf(a2 + bv.z);
  o.w = (f16)geluf(a3 + bv.w);
  *(f16x4*)(out + (size_t)n*HID + fo) = o;
}

// ---------------- GAT: per-node attention coefficients (fp16 feats) ----------------
__global__ __launch_bounds__(256) void k_attcoef(const f16* __restrict__ gfeat,
    const float* __restrict__ atts, const float* __restrict__ attd,
    float* __restrict__ a_src, float* __restrict__ a_dst){
  const int n = (int)((blockIdx.x*blockDim.x + threadIdx.x) >> 6);
  if (n >= NN) return;
  const int lane = threadIdx.x & 63;
  const int head = lane >> 3, sub = lane & 7;
  const int off = head*HC + sub*4;
  const f16x4 gv = *(const f16x4*)(gfeat + (size_t)n*HID + off);
  const float4 sv = *(const float4*)(atts + off);
  const float4 dv = *(const float4*)(attd + off);
  const float g0=(float)gv.x, g1=(float)gv.y, g2=(float)gv.z, g3=(float)gv.w;
  float ps = g0*sv.x + g1*sv.y + g2*sv.z + g3*sv.w;
  float pd = g0*dv.x + g1*dv.y + g2*dv.z + g3*dv.w;
  ps += __shfl_xor(ps,1); ps += __shfl_xor(ps,2); ps += __shfl_xor(ps,4);
  pd += __shfl_xor(pd,1); pd += __shfl_xor(pd,2); pd += __shfl_xor(pd,4);
  if (sub == 0){ a_src[n*NH+head] = ps; a_dst[n*NH+head] = pd; }
}

// ---------------- GAT: segment max + sum (wave per node, 8 edges x 8 heads) ----------------
__global__ __launch_bounds__(256) void k_gat_ms(const u32* __restrict__ col,
    const u32* __restrict__ start, const u32* __restrict__ cnt,
    const float* __restrict__ a_src, const float* __restrict__ a_dst,
    float* __restrict__ marr, float* __restrict__ sarr){
  const int n = (int)((blockIdx.x*blockDim.x + threadIdx.x) >> 6);
  if (n >= NN) return;
  const int lane = threadIdx.x & 63;
  const int h = lane & 7, e8 = lane >> 3;
  const u32 b = start[n], c = cnt[n];
  const float ad = a_dst[n*NH+h];
  float vmax = -1e30f;
  for (u32 k0=0; k0<c; k0+=8){
    const u32 ke = k0 + (u32)e8;
    float l = -1e30f;
    if (ke < c){
      const u32 s = col[b+ke];
      l = leakyf(a_src[s*NH+h] + ad);
    }
    l = fmaxf(l, __shfl_xor(l,8));
    l = fmaxf(l, __shfl_xor(l,16));
    l = fmaxf(l, __shfl_xor(l,32));
    vmax = fmaxf(vmax, l);
  }
  float ss = 0.f;
  for (u32 k0=0; k0<c; k0+=8){
    const u32 ke = k0 + (u32)e8;
    float p = 0.f;
    if (ke < c){
      const u32 s = col[b+ke];
      p = expf(leakyf(a_src[s*NH+h] + ad) - vmax);
    }
    p += __shfl_xor(p,8); p += __shfl_xor(p,16); p += __shfl_xor(p,32);
    ss += p;
  }
  if (lane < 8){ marr[n*NH+lane] = vmax; sarr[n*NH+lane] = ss; }
}

// ---------------- GAT: weighted aggregation + bias + relu -> h2 (f16) ----------------
__global__ __launch_bounds__(256) void k_gat_agg(const f16* __restrict__ gfeat,
    const u32* __restrict__ col, const u32* __restrict__ start, const u32* __restrict__ cnt,
    const float* __restrict__ a_src, const float* __restrict__ a_dst,
    const float* __restrict__ marr, const float* __restrict__ sarr,
    const float* __restrict__ b_att, f16* __restrict__ h2){
  const int n = (int)((blockIdx.x*blockDim.x + threadIdx.x) >> 6);
  if (n >= NN) return;
  const int lane = threadIdx.x & 63;
  const int head = lane >> 3;          // feats lane*4 -> head = lane*4/32
  const int fo = lane*4;
  const u32 b = start[n], e = b + cnt[n];
  const float mh = marr[n*NH+head];
  const float inv_s = 1.f / sarr[n*NH+head];
  const float ad = a_dst[n*NH+head];
  float a0=0.f,a1=0.f,a2=0.f,a3=0.f;
  // depth-2 software pipeline
  u32 s0 = col[b];
  float as0 = a_src[s0*NH+head];
  f16x4 v0 = *(const f16x4*)(gfeat + (size_t)s0*HID + fo);
  for (u32 k=b+1; k<e; ++k){
    const u32 s1 = col[k];
    const float as1 = a_src[s1*NH+head];
    const f16x4 v1 = *(const f16x4*)(gfeat + (size_t)s1*HID + fo);
    const float alpha = expf(leakyf(as0 + ad) - mh) * inv_s;
    a0 = fmaf(alpha, (float)v0.x, a0);
    a1 = fmaf(alpha, (float)v0.y, a1);
    a2 = fmaf(alpha, (float)v0.z, a2);
    a3 = fmaf(alpha, (float)v0.w, a3);
    v0 = v1; as0 = as1;
  }
  const float alpha = expf(leakyf(as0 + ad) - mh) * inv_s;
  a0 = fmaf(alpha, (float)v0.x, a0);
  a1 = fmaf(alpha, (float)v0.y, a1);
  a2 = fmaf(alpha, (float)v0.z, a2);
  a3 = fmaf(alpha, (float)v0.w, a3);
  const float4 bv = *(const float4*)(b_att + fo);
  f16x4 o;
  o.x = (f16)fmaxf(a0 + bv.x, 0.f);
  o.y = (f16)fmaxf(a1 + bv.y, 0.f);
  o.z = (f16)fmaxf(a2 + bv.z, 0.f);
  o.w = (f16)fmaxf(a3 + bv.w, 0.f);
  *(f16x4*)(h2 + (size_t)n*HID + fo) = o;
}

// ---------------- layer-3 agg: fp16 128-dim gather, +bias, f32 out (mu | logstd) ----------------
__global__ __launch_bounds__(256) void k_agg_out(const f16* __restrict__ p,
    const u32* __restrict__ col, const u32* __restrict__ start, const u32* __restrict__ cnt,
    const float* __restrict__ dinv, const float* __restrict__ b_mu, const float* __restrict__ b_ls,
    float* __restrict__ out){
  const int n = (int)((blockIdx.x*blockDim.x + threadIdx.x) >> 6);
  if (n >= NN) return;
  const int lane = threadIdx.x & 63;
  const u32 b = start[n], e = b + cnt[n];
  const float dd = dinv[n];
  const int fo = lane*2;
  float a0=0.f, a1=0.f;
  // depth-2 software pipeline
  u32 s0 = col[b];
  float di0 = dinv[s0];
  f16x2 v0 = *(const f16x2*)(p + (size_t)s0*PC + fo);
  for (u32 k=b+1; k<e; ++k){
    const u32 s1 = col[k];
    const float di1 = dinv[s1];
    const f16x2 v1 = *(const f16x2*)(p + (size_t)s1*PC + fo);
    const float nrm = dd * di0;
    a0 = fmaf(nrm, (float)v0.x, a0);
    a1 = fmaf(nrm, (float)v0.y, a1);
    v0 = v1; di0 = di1;
  }
  const float nrm = dd * di0;
  a0 = fmaf(nrm, (float)v0.x, a0);
  a1 = fmaf(nrm, (float)v0.y, a1);
  if (lane < 32){
    const int c = fo;                      // 0..62
    float2 o = make_float2(a0 + b_mu[c], a1 + b_mu[c+1]);
    *(float2*)(out + (size_t)n*OC + c) = o;
  } else {
    const int c = fo - OC;                 // 0..62
    float2 o = make_float2(a0 + b_ls[c], a1 + b_ls[c+1]);
    *(float2*)(out + (size_t)NN*OC + (size_t)n*OC + c) = o;
  }
}

extern "C" void kernel_launch(void* const* d_in, const int* in_sizes, int n_in,
                              void* d_out, int out_size, void* d_ws, size_t ws_size,
                              hipStream_t stream){
  const float* x    = (const float*)d_in[0];
  const int*   ei   = (const int*)d_in[1];
  const float* w1   = (const float*)d_in[2];
  const float* b1   = (const float*)d_in[3];
  const float* watt = (const float*)d_in[4];
  const float* atts = (const float*)d_in[5];
  const float* attd = (const float*)d_in[6];
  const float* batt = (const float*)d_in[7];
  const float* bmu  = (const float*)d_in[9];
  const float* wmu  = (const float*)d_in[8];
  const float* wls  = (const float*)d_in[10];
  const float* bls  = (const float*)d_in[11];
  const int* esrc = ei;
  const int* edst = ei + EE;

  char* p = (char*)d_ws;
  f16* bufA = (f16*)p;  p += (size_t)NN*HID*2;   // 25.6 MB: g1 (x@w1) -> h2
  f16* bufB = (f16*)p;  p += (size_t)NN*HID*2;   // 25.6 MB: h1 -> proj(128)
  f16* bufC = (f16*)p;  p += (size_t)NN*HID*2;   // 25.6 MB: g (GAT feats)
  bf16* w1hi = (bf16*)p; p += (size_t)HID*HID*2;
  bf16* w1lo = (bf16*)p; p += (size_t)HID*HID*2;
  f16* wahi  = (f16*)p;  p += (size_t)HID*HID*2;
  f16* walo  = (f16*)p;  p += (size_t)HID*HID*2;
  f16* wchi  = (f16*)p;  p += (size_t)PC*HID*2;
  f16* wclo  = (f16*)p;  p += (size_t)PC*HID*2;
  float* dinv = (float*)p; p += (size_t)NN*4;
  float* asr  = (float*)p; p += (size_t)NN*NH*4;
  float* ads  = (float*)p; p += (size_t)NN*NH*4;
  float* marr = (float*)p; p += (size_t)NN*NH*4;
  float* sarr = (float*)p; p += (size_t)NN*NH*4;
  u32*   cnt  = (u32*)p;   p += (size_t)NN*4;
  u32*   start= (u32*)p;   p += (size_t)NN*4;
  u32*   pos  = (u32*)p;   p += (size_t)NN*4;
  u32*   col  = (u32*)p;   p += (size_t)ET*4;
  u32*   counter = (u32*)p; p += 256;

  const int TB = 256;
  // CSR build (bucket order arbitrary -> no prefix scan needed)
  k_init <<<(NN+TB-1)/TB, TB, 0, stream>>>(cnt, counter);
  k_count<<<(EE+TB-1)/TB, TB, 0, stream>>>(edst, cnt);
  k_alloc<<<(NN+TB-1)/TB, TB, 0, stream>>>(cnt, counter, start, pos, dinv);
  k_fill <<<(ET+TB-1)/TB, TB, 0, stream>>>(esrc, edst, pos, col);
  // weight splits (tiny)
  k_wsplit_bf<HID><<<(HID*HID+TB-1)/TB, TB, 0, stream>>>(w1, w1hi, w1lo);
  k_wsplit_f16<HID><<<(HID*HID+TB-1)/TB, TB, 0, stream>>>(watt, wahi, walo, 0);
  k_wsplit_f16<OC> <<<(OC*HID+TB-1)/TB, TB, 0, stream>>>(wmu, wchi, wclo, 0);
  k_wsplit_f16<OC> <<<(OC*HID+TB-1)/TB, TB, 0, stream>>>(wls, wchi, wclo, OC);

  const int NWB = NN/4;            // gather kernels: 1 wave per node
  const int G64 = (NN + 63)/64;    // GEMM blocks: 64 rows each
  // layer 1: g1 = x@w1 ; h1 = gelu(agg(g1) + b1)
  k_gemm_f32A<HID,4,4><<<G64, TB, 0, stream>>>(x, w1hi, w1lo, bufA);
  k_aggH<<<NWB, TB, 0, stream>>>(bufA, col, start, cnt, dinv, b1, bufB);
  // GAT: g = h1@w_att ; attention ; h2 = relu(agg_att(g) + b_att)
  k_gemm_f16A<HID,4,4><<<G64, TB, 0, stream>>>(bufB, wahi, walo, bufC);
  k_attcoef<<<NWB, TB, 0, stream>>>(bufC, atts, attd, asr, ads);
  k_gat_ms <<<NWB, TB, 0, stream>>>(col, start, cnt, asr, ads, marr, sarr);
  k_gat_agg<<<NWB, TB, 0, stream>>>(bufC, col, start, cnt, asr, ads, marr, sarr, batt, bufA);
  // layer 3: project first (128 cols = mu||ls), then one 128-dim gather -> d_out
  k_gemm_f16A<PC,2,4><<<G64, TB, 0, stream>>>(bufA, wchi, wclo, bufB);
  k_agg_out<<<NWB, TB, 0, stream>>>(bufB, col, start, cnt, dinv, bmu, bls, (float*)d_out);
}